// Round 4
// baseline (130.680 us; speedup 1.0000x reference)
//
#include <hip/hip_runtime.h>
#include <math.h>

#define NC 1024
#define NF 16384
#define NPTS (2*NF + 2*NC)   // 34816 packed points / max-accumulators
#define TPB  256

typedef _Float16 f16x8 __attribute__((ext_vector_type(8)));
typedef float    f32x16 __attribute__((ext_vector_type(16)));

// Order-preserving float -> uint encoding (for atomicMax on floats incl. negatives)
__device__ __forceinline__ unsigned enc_f(float f) {
    unsigned u = __float_as_uint(f);
    return (u & 0x80000000u) ? ~u : (u | 0x80000000u);
}
__device__ __forceinline__ float dec_f(unsigned k) {
    unsigned u = (k & 0x80000000u) ? (k ^ 0x80000000u) : ~k;
    return __uint_as_float(u);
}

// Packed point-index layout (recs, hq, mm all share it):
//   [0, NF)            : ref_points_f             (pass A queries; pass B/D targets)
//   [NF, 2NF)          : src_points_f transformed (pass B queries; pass A/C targets)
//   [2NF, 2NF+NC)      : ref_points_c             (pass C queries)
//   [2NF+NC, 2NF+2NC)  : src_points_c transformed (pass D queries)
//
// f16 hi/lo split records for MFMA K-packing (K=16):
//   A rec: k = [qhx qhy qhz | qlx qly qlz | qhx qhy qhz | 1 1 | qlx qly qlz | 0 0]
//   B rec: k = [phx phy phz | phx phy phz | plx ply plz | -hh -hl | plx ply plz | 0 0]
// => sum_k A[k]B[k] = (qh+ql).(ph+pl) - h_p  (residual ~1e-5); verified absmax 0 (R2,R3).
__global__ __launch_bounds__(TPB) void prep_kernel(
    const float* __restrict__ refc, const float* __restrict__ srcc,
    const float* __restrict__ reff, const float* __restrict__ srcf,
    const float* __restrict__ T,
    f16x8* __restrict__ a0, f16x8* __restrict__ a1,
    f16x8* __restrict__ b0, f16x8* __restrict__ b1,
    float* __restrict__ hqv, unsigned* __restrict__ mm)
{
    int i = blockIdx.x * blockDim.x + threadIdx.x;
    if (i >= NPTS) return;
    mm[i] = 0u;  // below every encoded float
    float x, y, z;
    bool xform;
    if (i < NF) {
        const float* p = reff + 3*i;             x=p[0]; y=p[1]; z=p[2]; xform=false;
    } else if (i < 2*NF) {
        const float* p = srcf + 3*(i - NF);      x=p[0]; y=p[1]; z=p[2]; xform=true;
    } else if (i < 2*NF + NC) {
        const float* p = refc + 3*(i - 2*NF);    x=p[0]; y=p[1]; z=p[2]; xform=false;
    } else {
        const float* p = srcc + 3*(i - 2*NF-NC); x=p[0]; y=p[1]; z=p[2]; xform=true;
    }
    if (xform) {
        float nx = T[0]*x + T[1]*y + T[2]*z  + T[3];
        float ny = T[4]*x + T[5]*y + T[6]*z  + T[7];
        float nz = T[8]*x + T[9]*y + T[10]*z + T[11];
        x = nx; y = ny; z = nz;
    }
    float h = 0.5f*(x*x + y*y + z*z);
    hqv[i] = h;
    _Float16 hx = (_Float16)x; _Float16 hy = (_Float16)y; _Float16 hz = (_Float16)z;
    _Float16 lx = (_Float16)(x - (float)hx);
    _Float16 ly = (_Float16)(y - (float)hy);
    _Float16 lz = (_Float16)(z - (float)hz);
    _Float16 hh = (_Float16)h;
    _Float16 hl = (_Float16)(h - (float)hh);
    _Float16 one = (_Float16)1.0f, zz = (_Float16)0.0f;
    a0[i] = (f16x8){hx, hy, hz, lx, ly, lz, hx, hy};
    a1[i] = (f16x8){hz, one, one, lx, ly, lz, zz, zz};
    b0[i] = (f16x8){hx, hy, hz, hx, hy, hz, lx, ly};
    b1[i] = (f16x8){lz, (_Float16)(-hh), (_Float16)(-hl), lx, ly, lz, zz, zz};
}

// MFMA min-distance kernel, LDS-traffic-optimized:
//  - block: 256 query rows x 2048 targets (64KB LDS staging)
//  - wave w owns rows [w*64, w*64+64) as TWO 32-row A-tiles -> each B-tile
//    ds_read is reused by 2 MFMAs (0.5 reads/MFMA vs R3's 1.0)
//  - 2048-target chunks halve block count -> halve per-block transpose epilogue
// Grid 1088:
//   A [0,512):     rb in [0,64) x ck in [0,8)   Q=ref_f    T=src_f_t
//   B [512,1024):  same shape                    Q=src_f_t  T=ref_f
//   C [1024,1056): rb in [0,4)  x ck in [0,8)   Q=ref_c    T=src_f_t
//   D [1056,1088): same shape                    Q=src_c_t  T=ref_f
__global__ __launch_bounds__(TPB, 2) void minmax_kernel(
    const f16x8* __restrict__ a0g, const f16x8* __restrict__ a1g,
    const f16x8* __restrict__ b0g, const f16x8* __restrict__ b1g,
    unsigned* __restrict__ mm)
{
    // 64KB: plane0 = 2048 b0-records, plane1 = 2048 b1-records.
    // Tail-reused after barrier as 4 x 8704B per-wave transpose scratch.
    __shared__ __align__(16) char ldsraw[65536];
    f16x8* sbuf = (f16x8*)ldsraw;

    int b = blockIdx.x;
    int qoff, toff, rb, ck;
    if (b < 512)       { rb = b >> 3;             ck = b & 7;  qoff = 0;          toff = NF; }
    else if (b < 1024) { int bb=b-512;  rb=bb>>3; ck=bb&7;     qoff = NF;         toff = 0;  }
    else if (b < 1056) { int bb=b-1024; rb=bb>>3; ck=bb&7;     qoff = 2*NF;       toff = NF; }
    else               { int bb=b-1056; rb=bb>>3; ck=bb&7;     qoff = 2*NF + NC;  toff = 0;  }
    int rbase = qoff + rb * 256;
    int tbase = toff + ck * 2048;

    int tid = threadIdx.x, wv = tid >> 6, ln = tid & 63;

    // stage 4096 records (16B/lane, coalesced dwordx4)
#pragma unroll
    for (int k = 0; k < 16; k++) {
        int i = tid + k * 256;
        sbuf[i] = (i < 2048) ? b0g[tbase + i] : b1g[tbase + i - 2048];
    }

    int m  = ln & 31;        // A-row within tile / B-col (target) within tile
    int hf = ln >> 5;        // K-group select
    int rA = rbase + wv * 64 + m;
    f16x8 aA = hf ? a1g[rA]      : a0g[rA];        // rows [wv*64, wv*64+32)
    f16x8 aB = hf ? a1g[rA + 32] : a0g[rA + 32];   // rows [wv*64+32, +64)

    f32x16 acc0, acc1;
#pragma unroll
    for (int r = 0; r < 16; r++) { acc0[r] = -3.0e38f; acc1[r] = -3.0e38f; }
    f32x16 zf = {};

    __syncthreads();

    const f16x8* sb = sbuf + hf * 2048 + m;   // imm offsets cover u*1024B below
#pragma unroll 4
    for (int u = 0; u < 32; ++u) {            // 2 B-tiles (64 targets) per iter
        f16x8 bA = sb[u * 64];
        f16x8 bB = sb[u * 64 + 32];
        f32x16 d0 = __builtin_amdgcn_mfma_f32_32x32x16_f16(aA, bA, zf, 0, 0, 0);
        f32x16 d1 = __builtin_amdgcn_mfma_f32_32x32x16_f16(aA, bB, zf, 0, 0, 0);
#pragma unroll
        for (int r = 0; r < 16; r++)
            acc0[r] = fmaxf(fmaxf(acc0[r], d0[r]), d1[r]);   // -> v_max3_f32
        f32x16 d2 = __builtin_amdgcn_mfma_f32_32x32x16_f16(aB, bA, zf, 0, 0, 0);
        f32x16 d3 = __builtin_amdgcn_mfma_f32_32x32x16_f16(aB, bB, zf, 0, 0, 0);
#pragma unroll
        for (int r = 0; r < 16; r++)
            acc1[r] = fmaxf(fmaxf(acc1[r], d2[r]), d3[r]);
    }

    __syncthreads();   // all waves done reading sbuf before scratch overwrite

    // Col-reduce via per-wave LDS transpose (no further barriers: scratch is
    // wave-private). C/D layout: col=lane&31, row=(r&3)+8*(r>>2)+4*hf.
    // Row stride 34 floats (136B): writes (2row+m)%32 2-way free; float2 reads
    // (2ln+2k)%32 2-way free — measured 0 conflicts in R2.
    float* scr = (float*)(ldsraw + wv * 8704);     // 64 rows x 34 floats
#pragma unroll
    for (int r = 0; r < 16; r++) {
        int row = (r & 3) + 8 * (r >> 2) + 4 * hf;
        scr[row * 34 + m]        = acc0[r];
        scr[(row + 32) * 34 + m] = acc1[r];
    }
    __builtin_amdgcn_s_waitcnt(0);   // lgkmcnt(0): own-wave LDS writes visible

    const float2* rv = (const float2*)(ldsraw + wv * 8704 + ln * 136);
    float mx = -3.0e38f;
#pragma unroll
    for (int k = 0; k < 16; k += 2) {
        float2 v0 = rv[k], v1 = rv[k + 1];
        mx = fmaxf(fmaxf(mx, fmaxf(v0.x, v0.y)), fmaxf(v1.x, v1.y));
    }
    atomicMax(&mm[rbase + wv * 64 + ln], enc_f(mx));
}

// Block 0: n2p loss (2048 elems, thr=0.5). Block 1: p2p loss (32768 elems, thr=0.1).
__global__ __launch_bounds__(1024) void loss_kernel(
    const float* __restrict__ hqv, const unsigned* __restrict__ mm,
    const float* __restrict__ p2p_ref, const float* __restrict__ p2p_src,
    const float* __restrict__ n2p_ref, const float* __restrict__ n2p_src,
    float* __restrict__ out)
{
    __shared__ float rc[16], rp[16], rn[16];
    bool is_p2p = (blockIdx.x == 1);
    int N = is_p2p ? 2*NF : 2*NC;
    float thr_half = is_p2p ? 0.5f*(0.1f*0.1f) : 0.5f*(0.5f*0.5f);

    float cnt = 0.0f, spos = 0.0f, sneg = 0.0f;
    for (int i = threadIdx.x; i < N; i += 1024) {
        float score; int qi;
        if (is_p2p) {
            if (i < NF) { score = p2p_src[i];      qi = NF + i; }           // src_gt: pass B
            else        { score = p2p_ref[i - NF]; qi = i - NF; }           // ref_gt: pass A
        } else {
            if (i < NC) { score = n2p_src[i];      qi = 2*NF + NC + i; }    // src_gt_n: pass D
            else        { score = n2p_ref[i - NC]; qi = 2*NF + (i - NC); }  // ref_gt_n: pass C
        }
        float maxm = dec_f(mm[qi]);
        float hq = hqv[qi];            // |q|^2 / 2 (fp32 exact)
        bool g = maxm > (hq - thr_half);
        if (g) { cnt += 1.0f; spos -= logf(score); }
        else   { sneg -= log1pf(-score); }
    }

    int lane = threadIdx.x & 63, wid = threadIdx.x >> 6;
#pragma unroll
    for (int off = 32; off > 0; off >>= 1) {
        cnt  += __shfl_down(cnt,  off, 64);
        spos += __shfl_down(spos, off, 64);
        sneg += __shfl_down(sneg, off, 64);
    }
    if (lane == 0) { rc[wid] = cnt; rp[wid] = spos; rn[wid] = sneg; }
    __syncthreads();
    if (threadIdx.x == 0) {
        float c = 0, sp = 0, sn = 0;
        for (int w = 0; w < 16; w++) { c += rc[w]; sp += rp[w]; sn += rn[w]; }
        float wneg = c / (float)N;
        float wpos = 1.0f - wneg;
        out[blockIdx.x] = (wpos * sp + wneg * sn) / (float)N;   // out[0]=n2p, out[1]=p2p
    }
}

extern "C" void kernel_launch(void* const* d_in, const int* in_sizes, int n_in,
                              void* d_out, int out_size, void* d_ws, size_t ws_size,
                              hipStream_t stream) {
    (void)in_sizes; (void)n_in; (void)out_size; (void)ws_size;
    const float* refc = (const float*)d_in[0];
    const float* srcc = (const float*)d_in[1];
    const float* reff = (const float*)d_in[2];
    const float* srcf = (const float*)d_in[3];
    const float* T    = (const float*)d_in[4];
    const float* p2p_ref = (const float*)d_in[5];
    const float* p2p_src = (const float*)d_in[6];
    const float* n2p_ref = (const float*)d_in[7];
    const float* n2p_src = (const float*)d_in[8];
    float* out = (float*)d_out;

    f16x8* a0 = (f16x8*)d_ws;
    f16x8* a1 = a0 + NPTS;
    f16x8* b0 = a1 + NPTS;
    f16x8* b1 = b0 + NPTS;
    float* hqv = (float*)(b1 + NPTS);
    unsigned* mm = (unsigned*)(hqv + NPTS);   // total ws use: 72*NPTS = ~2.5 MB

    prep_kernel<<<(NPTS + TPB - 1) / TPB, TPB, 0, stream>>>(
        refc, srcc, reff, srcf, T, a0, a1, b0, b1, hqv, mm);
    minmax_kernel<<<1088, TPB, 0, stream>>>(a0, a1, b0, b1, mm);
    loss_kernel<<<2, 1024, 0, stream>>>(hqv, mm, p2p_ref, p2p_src, n2p_ref, n2p_src, out);
}

// Round 5
// 126.586 us; speedup vs baseline: 1.0323x; 1.0323x over previous
//
#include <hip/hip_runtime.h>
#include <math.h>

#define NC 1024
#define NF 16384
#define NPTS (2*NF + 2*NC)   // 34816 packed points / max-accumulators
#define TPB  256

typedef _Float16 f16x8 __attribute__((ext_vector_type(8)));
typedef float    f32x16 __attribute__((ext_vector_type(16)));

// Order-preserving float -> uint encoding (for atomicMax on floats incl. negatives)
__device__ __forceinline__ unsigned enc_f(float f) {
    unsigned u = __float_as_uint(f);
    return (u & 0x80000000u) ? ~u : (u | 0x80000000u);
}
__device__ __forceinline__ float dec_f(unsigned k) {
    unsigned u = (k & 0x80000000u) ? (k ^ 0x80000000u) : ~k;
    return __uint_as_float(u);
}

// Packed point-index layout (recs, hq, mm all share it):
//   [0, NF)            : ref_points_f             (pass A queries; pass B/D targets)
//   [NF, 2NF)          : src_points_f transformed (pass B queries; pass A/C targets)
//   [2NF, 2NF+NC)      : ref_points_c             (pass C queries)
//   [2NF+NC, 2NF+2NC)  : src_points_c transformed (pass D queries)
//
// f16 hi/lo split records for MFMA K-packing (K=16):
//   A rec: k = [qhx qhy qhz | qlx qly qlz | qhx qhy qhz | 1 1 | qlx qly qlz | 0 0]
//   B rec: k = [phx phy phz | phx phy phz | plx ply plz | -hh -hl | plx ply plz | 0 0]
// => sum_k A[k]B[k] = (qh+ql).(ph+pl) - h_p  (residual ~1e-5); verified absmax 0 (R2-R4).
__global__ __launch_bounds__(TPB) void prep_kernel(
    const float* __restrict__ refc, const float* __restrict__ srcc,
    const float* __restrict__ reff, const float* __restrict__ srcf,
    const float* __restrict__ T,
    f16x8* __restrict__ a0, f16x8* __restrict__ a1,
    f16x8* __restrict__ b0, f16x8* __restrict__ b1,
    float* __restrict__ hqv, unsigned* __restrict__ mm)
{
    int i = blockIdx.x * blockDim.x + threadIdx.x;
    if (i >= NPTS) return;
    mm[i] = 0u;  // below every encoded float
    float x, y, z;
    bool xform;
    if (i < NF) {
        const float* p = reff + 3*i;             x=p[0]; y=p[1]; z=p[2]; xform=false;
    } else if (i < 2*NF) {
        const float* p = srcf + 3*(i - NF);      x=p[0]; y=p[1]; z=p[2]; xform=true;
    } else if (i < 2*NF + NC) {
        const float* p = refc + 3*(i - 2*NF);    x=p[0]; y=p[1]; z=p[2]; xform=false;
    } else {
        const float* p = srcc + 3*(i - 2*NF-NC); x=p[0]; y=p[1]; z=p[2]; xform=true;
    }
    if (xform) {
        float nx = T[0]*x + T[1]*y + T[2]*z  + T[3];
        float ny = T[4]*x + T[5]*y + T[6]*z  + T[7];
        float nz = T[8]*x + T[9]*y + T[10]*z + T[11];
        x = nx; y = ny; z = nz;
    }
    float h = 0.5f*(x*x + y*y + z*z);
    hqv[i] = h;
    _Float16 hx = (_Float16)x; _Float16 hy = (_Float16)y; _Float16 hz = (_Float16)z;
    _Float16 lx = (_Float16)(x - (float)hx);
    _Float16 ly = (_Float16)(y - (float)hy);
    _Float16 lz = (_Float16)(z - (float)hz);
    _Float16 hh = (_Float16)h;
    _Float16 hl = (_Float16)(h - (float)hh);
    _Float16 one = (_Float16)1.0f, zz = (_Float16)0.0f;
    a0[i] = (f16x8){hx, hy, hz, lx, ly, lz, hx, hy};
    a1[i] = (f16x8){hz, one, one, lx, ly, lz, zz, zz};
    b0[i] = (f16x8){hx, hy, hz, hx, hy, hz, lx, ly};
    b1[i] = (f16x8){lz, (_Float16)(-hh), (_Float16)(-hl), lx, ly, lz, zz, zz};
}

// MFMA min-distance kernel.
// Shape: block = 256 rows x 1024 targets; wave w owns rows [w*64, w*64+64) as
// TWO 32-row A-tiles (each ds_read_b128 of a B-tile feeds 2 MFMAs).
// Register budget: __launch_bounds__(256,4) caps at 128 VGPR so the live set
// (aA/aB 8 + acc 32 + one 2-MFMA burst's d 32 + addr ~15) stays in ARCH VGPRs
// -> no per-iteration v_accvgpr shuffling (R3/R4 pathology, VGPR_Count=60,
// VALUBusy 81%). LDS 34816B -> 4 blocks/CU -> 16 waves/CU for latency hiding.
// Grid 2176:
//   A [0,1024):     rb in [0,64) x ck in [0,16)  Q=ref_f    T=src_f_t
//   B [1024,2048):  same shape                    Q=src_f_t  T=ref_f
//   C [2048,2112):  rb in [0,4)  x ck in [0,16)  Q=ref_c    T=src_f_t
//   D [2112,2176):  same shape                    Q=src_c_t  T=ref_f
__global__ __launch_bounds__(TPB, 4) void minmax_kernel(
    const f16x8* __restrict__ a0g, const f16x8* __restrict__ a1g,
    const f16x8* __restrict__ b0g, const f16x8* __restrict__ b1g,
    unsigned* __restrict__ mm)
{
    // 32KB staging (plane0 = 1024 b0-recs, plane1 = 1024 b1-recs);
    // reused after barrier as 4 x 8704B per-wave transpose scratch (34816B).
    __shared__ __align__(16) char ldsraw[34816];
    f16x8* sbuf = (f16x8*)ldsraw;

    int b = blockIdx.x;
    int qoff, toff, rb, ck;
    if (b < 1024)      { rb = b >> 4;              ck = b & 15; qoff = 0;          toff = NF; }
    else if (b < 2048) { int bb=b-1024; rb=bb>>4;  ck=bb&15;    qoff = NF;         toff = 0;  }
    else if (b < 2112) { int bb=b-2048; rb=bb>>4;  ck=bb&15;    qoff = 2*NF;       toff = NF; }
    else               { int bb=b-2112; rb=bb>>4;  ck=bb&15;    qoff = 2*NF + NC;  toff = 0;  }
    int rbase = qoff + rb * 256;
    int tbase = toff + ck * 1024;

    int tid = threadIdx.x, wv = tid >> 6, ln = tid & 63;

    // stage 2048 records (16B/lane, coalesced dwordx4)
#pragma unroll
    for (int k = 0; k < 8; k++) {
        int i = tid + k * 256;
        sbuf[i] = (i < 1024) ? b0g[tbase + i] : b1g[tbase + i - 1024];
    }

    int m  = ln & 31;        // A-row within tile / B-col (target) within tile
    int hf = ln >> 5;        // K-group select
    int rA = rbase + wv * 64 + m;
    f16x8 aA = hf ? a1g[rA]      : a0g[rA];        // rows [wv*64, wv*64+32)
    f16x8 aB = hf ? a1g[rA + 32] : a0g[rA + 32];   // rows [wv*64+32, +64)

    f32x16 acc0, acc1;
#pragma unroll
    for (int r = 0; r < 16; r++) { acc0[r] = -3.0e38f; acc1[r] = -3.0e38f; }
    f32x16 zf = {};

    __syncthreads();

    const f16x8* sb = sbuf + hf * 1024 + m;
#pragma unroll 2
    for (int u = 0; u < 16; ++u) {            // 2 B-tiles (64 targets) per iter
        f16x8 bA = sb[u * 64];
        f16x8 bB = sb[u * 64 + 32];
        // burst 1: only d0,d1 transient (32 regs), then retire into acc0
        f32x16 d0 = __builtin_amdgcn_mfma_f32_32x32x16_f16(aA, bA, zf, 0, 0, 0);
        f32x16 d1 = __builtin_amdgcn_mfma_f32_32x32x16_f16(aA, bB, zf, 0, 0, 0);
#pragma unroll
        for (int r = 0; r < 16; r++)
            acc0[r] = fmaxf(fmaxf(acc0[r], d0[r]), d1[r]);   // -> v_max3_f32
        // burst 2
        f32x16 d2 = __builtin_amdgcn_mfma_f32_32x32x16_f16(aB, bA, zf, 0, 0, 0);
        f32x16 d3 = __builtin_amdgcn_mfma_f32_32x32x16_f16(aB, bB, zf, 0, 0, 0);
#pragma unroll
        for (int r = 0; r < 16; r++)
            acc1[r] = fmaxf(fmaxf(acc1[r], d2[r]), d3[r]);
    }

    __syncthreads();   // all waves done reading sbuf before scratch overwrite

    // Col-reduce via per-wave LDS transpose (wave-private scratch, no barrier).
    // C/D layout: col=lane&31, row=(r&3)+8*(r>>2)+4*hf.  Row stride 34 floats:
    // writes (2row+m)%32 conflict-free; float2 reads 2-way (free). 0 conflicts
    // measured R2-R4.
    float* scr = (float*)(ldsraw + wv * 8704);     // 64 rows x 34 floats
#pragma unroll
    for (int r = 0; r < 16; r++) {
        int row = (r & 3) + 8 * (r >> 2) + 4 * hf;
        scr[row * 34 + m]        = acc0[r];
        scr[(row + 32) * 34 + m] = acc1[r];
    }
    __builtin_amdgcn_s_waitcnt(0);   // own-wave LDS writes visible

    const float2* rv = (const float2*)(ldsraw + wv * 8704 + ln * 136);
    float mx = -3.0e38f;
#pragma unroll
    for (int k = 0; k < 16; k += 2) {
        float2 v0 = rv[k], v1 = rv[k + 1];
        mx = fmaxf(fmaxf(mx, fmaxf(v0.x, v0.y)), fmaxf(v1.x, v1.y));
    }
    atomicMax(&mm[rbase + wv * 64 + ln], enc_f(mx));
}

// Block 0: n2p loss (2048 elems, thr=0.5). Block 1: p2p loss (32768 elems, thr=0.1).
__global__ __launch_bounds__(1024) void loss_kernel(
    const float* __restrict__ hqv, const unsigned* __restrict__ mm,
    const float* __restrict__ p2p_ref, const float* __restrict__ p2p_src,
    const float* __restrict__ n2p_ref, const float* __restrict__ n2p_src,
    float* __restrict__ out)
{
    __shared__ float rc[16], rp[16], rn[16];
    bool is_p2p = (blockIdx.x == 1);
    int N = is_p2p ? 2*NF : 2*NC;
    float thr_half = is_p2p ? 0.5f*(0.1f*0.1f) : 0.5f*(0.5f*0.5f);

    float cnt = 0.0f, spos = 0.0f, sneg = 0.0f;
    for (int i = threadIdx.x; i < N; i += 1024) {
        float score; int qi;
        if (is_p2p) {
            if (i < NF) { score = p2p_src[i];      qi = NF + i; }           // src_gt: pass B
            else        { score = p2p_ref[i - NF]; qi = i - NF; }           // ref_gt: pass A
        } else {
            if (i < NC) { score = n2p_src[i];      qi = 2*NF + NC + i; }    // src_gt_n: pass D
            else        { score = n2p_ref[i - NC]; qi = 2*NF + (i - NC); }  // ref_gt_n: pass C
        }
        float maxm = dec_f(mm[qi]);
        float hq = hqv[qi];            // |q|^2 / 2 (fp32 exact)
        bool g = maxm > (hq - thr_half);
        if (g) { cnt += 1.0f; spos -= logf(score); }
        else   { sneg -= log1pf(-score); }
    }

    int lane = threadIdx.x & 63, wid = threadIdx.x >> 6;
#pragma unroll
    for (int off = 32; off > 0; off >>= 1) {
        cnt  += __shfl_down(cnt,  off, 64);
        spos += __shfl_down(spos, off, 64);
        sneg += __shfl_down(sneg, off, 64);
    }
    if (lane == 0) { rc[wid] = cnt; rp[wid] = spos; rn[wid] = sneg; }
    __syncthreads();
    if (threadIdx.x == 0) {
        float c = 0, sp = 0, sn = 0;
        for (int w = 0; w < 16; w++) { c += rc[w]; sp += rp[w]; sn += rn[w]; }
        float wneg = c / (float)N;
        float wpos = 1.0f - wneg;
        out[blockIdx.x] = (wpos * sp + wneg * sn) / (float)N;   // out[0]=n2p, out[1]=p2p
    }
}

extern "C" void kernel_launch(void* const* d_in, const int* in_sizes, int n_in,
                              void* d_out, int out_size, void* d_ws, size_t ws_size,
                              hipStream_t stream) {
    (void)in_sizes; (void)n_in; (void)out_size; (void)ws_size;
    const float* refc = (const float*)d_in[0];
    const float* srcc = (const float*)d_in[1];
    const float* reff = (const float*)d_in[2];
    const float* srcf = (const float*)d_in[3];
    const float* T    = (const float*)d_in[4];
    const float* p2p_ref = (const float*)d_in[5];
    const float* p2p_src = (const float*)d_in[6];
    const float* n2p_ref = (const float*)d_in[7];
    const float* n2p_src = (const float*)d_in[8];
    float* out = (float*)d_out;

    f16x8* a0 = (f16x8*)d_ws;
    f16x8* a1 = a0 + NPTS;
    f16x8* b0 = a1 + NPTS;
    f16x8* b1 = b0 + NPTS;
    float* hqv = (float*)(b1 + NPTS);
    unsigned* mm = (unsigned*)(hqv + NPTS);   // total ws use: 72*NPTS = ~2.5 MB

    prep_kernel<<<(NPTS + TPB - 1) / TPB, TPB, 0, stream>>>(
        refc, srcc, reff, srcf, T, a0, a1, b0, b1, hqv, mm);
    minmax_kernel<<<2176, TPB, 0, stream>>>(a0, a1, b0, b1, mm);
    loss_kernel<<<2, 1024, 0, stream>>>(hqv, mm, p2p_ref, p2p_src, n2p_ref, n2p_src, out);
}

// Round 6
// 125.290 us; speedup vs baseline: 1.0430x; 1.0103x over previous
//
#include <hip/hip_runtime.h>
#include <math.h>

#define NC 1024
#define NF 16384
#define NPTS (2*NF + 2*NC)   // 34816 packed points / max-accumulators
#define TPB  256

typedef _Float16 f16x8 __attribute__((ext_vector_type(8)));
typedef float    f32x16 __attribute__((ext_vector_type(16)));

// Order-preserving float -> uint encoding (for atomicMax on floats incl. negatives)
__device__ __forceinline__ unsigned enc_f(float f) {
    unsigned u = __float_as_uint(f);
    return (u & 0x80000000u) ? ~u : (u | 0x80000000u);
}
__device__ __forceinline__ float dec_f(unsigned k) {
    unsigned u = (k & 0x80000000u) ? (k ^ 0x80000000u) : ~k;
    return __uint_as_float(u);
}

// VGPR-form MFMA via inline asm. The __builtin_ path allocates D (and acc) in
// AGPRs no matter the VGPR budget (R3: VGPR_Count=60 < live set; R4/R5
// launch_bounds sweeps neutral), and our max-reduction reads D with VALU every
// iteration -> per-iter v_accvgpr traffic (VALUBusy 81%, 6x ideal instr count).
// "=&v" forces a VGPR tuple dst (earlyclobber: MFMA dst must not alias A/B);
// literal 0 for C is a legal inline constant (ISA §10).
#define MFMA_V(d, a, b) \
    asm("v_mfma_f32_32x32x16_f16 %0, %1, %2, 0" : "=&v"(d) : "v"(a), "v"(b))

// Packed point-index layout (recs, hq, mm all share it):
//   [0, NF)            : ref_points_f             (pass A queries; pass B/D targets)
//   [NF, 2NF)          : src_points_f transformed (pass B queries; pass A/C targets)
//   [2NF, 2NF+NC)      : ref_points_c             (pass C queries)
//   [2NF+NC, 2NF+2NC)  : src_points_c transformed (pass D queries)
//
// f16 hi/lo split records for MFMA K-packing (K=16):
//   A rec: k = [qhx qhy qhz | qlx qly qlz | qhx qhy qhz | 1 1 | qlx qly qlz | 0 0]
//   B rec: k = [phx phy phz | phx phy phz | plx ply plz | -hh -hl | plx ply plz | 0 0]
// => sum_k A[k]B[k] = (qh+ql).(ph+pl) - h_p  (residual ~1e-5); verified absmax 0 (R2-R5).
__global__ __launch_bounds__(TPB) void prep_kernel(
    const float* __restrict__ refc, const float* __restrict__ srcc,
    const float* __restrict__ reff, const float* __restrict__ srcf,
    const float* __restrict__ T,
    f16x8* __restrict__ a0, f16x8* __restrict__ a1,
    f16x8* __restrict__ b0, f16x8* __restrict__ b1,
    float* __restrict__ hqv, unsigned* __restrict__ mm)
{
    int i = blockIdx.x * blockDim.x + threadIdx.x;
    if (i >= NPTS) return;
    mm[i] = 0u;  // below every encoded float
    float x, y, z;
    bool xform;
    if (i < NF) {
        const float* p = reff + 3*i;             x=p[0]; y=p[1]; z=p[2]; xform=false;
    } else if (i < 2*NF) {
        const float* p = srcf + 3*(i - NF);      x=p[0]; y=p[1]; z=p[2]; xform=true;
    } else if (i < 2*NF + NC) {
        const float* p = refc + 3*(i - 2*NF);    x=p[0]; y=p[1]; z=p[2]; xform=false;
    } else {
        const float* p = srcc + 3*(i - 2*NF-NC); x=p[0]; y=p[1]; z=p[2]; xform=true;
    }
    if (xform) {
        float nx = T[0]*x + T[1]*y + T[2]*z  + T[3];
        float ny = T[4]*x + T[5]*y + T[6]*z  + T[7];
        float nz = T[8]*x + T[9]*y + T[10]*z + T[11];
        x = nx; y = ny; z = nz;
    }
    float h = 0.5f*(x*x + y*y + z*z);
    hqv[i] = h;
    _Float16 hx = (_Float16)x; _Float16 hy = (_Float16)y; _Float16 hz = (_Float16)z;
    _Float16 lx = (_Float16)(x - (float)hx);
    _Float16 ly = (_Float16)(y - (float)hy);
    _Float16 lz = (_Float16)(z - (float)hz);
    _Float16 hh = (_Float16)h;
    _Float16 hl = (_Float16)(h - (float)hh);
    _Float16 one = (_Float16)1.0f, zz = (_Float16)0.0f;
    a0[i] = (f16x8){hx, hy, hz, lx, ly, lz, hx, hy};
    a1[i] = (f16x8){hz, one, one, lx, ly, lz, zz, zz};
    b0[i] = (f16x8){hx, hy, hz, hx, hy, hz, lx, ly};
    b1[i] = (f16x8){lz, (_Float16)(-hh), (_Float16)(-hl), lx, ly, lz, zz, zz};
}

// MFMA min-distance kernel.
// Block = 256 rows x 1024 targets; wave w owns rows [w*64, w*64+64) as two
// 32-row A-tiles (each B-tile ds_read feeds 2 MFMAs). Inner iter: issue 4
// VGPR-form MFMAs back-to-back (32 cyc issue covers the D-read hazard),
// prefetch next B-tiles under them, then retire with v_max3 chains.
// Grid 2176:
//   A [0,1024):     rb in [0,64) x ck in [0,16)  Q=ref_f    T=src_f_t
//   B [1024,2048):  same shape                    Q=src_f_t  T=ref_f
//   C [2048,2112):  rb in [0,4)  x ck in [0,16)  Q=ref_c    T=src_f_t
//   D [2112,2176):  same shape                    Q=src_c_t  T=ref_f
__global__ __launch_bounds__(TPB, 4) void minmax_kernel(
    const f16x8* __restrict__ a0g, const f16x8* __restrict__ a1g,
    const f16x8* __restrict__ b0g, const f16x8* __restrict__ b1g,
    unsigned* __restrict__ mm)
{
    // 32KB staging (plane0 = 1024 b0-recs, plane1 = 1024 b1-recs);
    // reused after barrier as 4 x 8704B per-wave transpose scratch (34816B).
    __shared__ __align__(16) char ldsraw[34816];
    f16x8* sbuf = (f16x8*)ldsraw;

    int b = blockIdx.x;
    int qoff, toff, rb, ck;
    if (b < 1024)      { rb = b >> 4;              ck = b & 15; qoff = 0;          toff = NF; }
    else if (b < 2048) { int bb=b-1024; rb=bb>>4;  ck=bb&15;    qoff = NF;         toff = 0;  }
    else if (b < 2112) { int bb=b-2048; rb=bb>>4;  ck=bb&15;    qoff = 2*NF;       toff = NF; }
    else               { int bb=b-2112; rb=bb>>4;  ck=bb&15;    qoff = 2*NF + NC;  toff = 0;  }
    int rbase = qoff + rb * 256;
    int tbase = toff + ck * 1024;

    int tid = threadIdx.x, wv = tid >> 6, ln = tid & 63;

    // stage 2048 records (16B/lane, coalesced dwordx4)
#pragma unroll
    for (int k = 0; k < 8; k++) {
        int i = tid + k * 256;
        sbuf[i] = (i < 1024) ? b0g[tbase + i] : b1g[tbase + i - 1024];
    }

    int m  = ln & 31;        // A-row within tile / B-col (target) within tile
    int hf = ln >> 5;        // K-group select
    int rA = rbase + wv * 64 + m;
    f16x8 aA = hf ? a1g[rA]      : a0g[rA];        // rows [wv*64, wv*64+32)
    f16x8 aB = hf ? a1g[rA + 32] : a0g[rA + 32];   // rows [wv*64+32, +64)

    f32x16 acc0, acc1;
#pragma unroll
    for (int r = 0; r < 16; r++) { acc0[r] = -3.0e38f; acc1[r] = -3.0e38f; }

    __syncthreads();

    const f16x8* sb = sbuf + hf * 1024 + m;
    f16x8 bA = sb[0], bB = sb[32];
    for (int u = 0; u < 16; ++u) {            // 2 B-tiles (64 targets) per iter
        f32x16 d0, d1, d2, d3;
        MFMA_V(d0, aA, bA);
        MFMA_V(d1, aA, bB);
        MFMA_V(d2, aB, bA);
        MFMA_V(d3, aB, bB);
        if (u < 15) {                          // prefetch under the MFMAs
            bA = sb[(u + 1) * 64];
            bB = sb[(u + 1) * 64 + 32];
        }
#pragma unroll
        for (int r = 0; r < 16; r++)
            acc0[r] = fmaxf(fmaxf(acc0[r], d0[r]), d1[r]);   // -> v_max3_f32
#pragma unroll
        for (int r = 0; r < 16; r++)
            acc1[r] = fmaxf(fmaxf(acc1[r], d2[r]), d3[r]);
    }

    __syncthreads();   // all waves done reading sbuf before scratch overwrite

    // Col-reduce via per-wave LDS transpose (wave-private scratch, no barrier).
    // C/D layout: col=lane&31, row=(r&3)+8*(r>>2)+4*hf.  Row stride 34 floats:
    // writes (2row+m)%32 conflict-free; float2 reads 2-way (free). 0 conflicts
    // measured R2-R5.
    float* scr = (float*)(ldsraw + wv * 8704);     // 64 rows x 34 floats
#pragma unroll
    for (int r = 0; r < 16; r++) {
        int row = (r & 3) + 8 * (r >> 2) + 4 * hf;
        scr[row * 34 + m]        = acc0[r];
        scr[(row + 32) * 34 + m] = acc1[r];
    }
    __builtin_amdgcn_s_waitcnt(0);   // own-wave LDS writes visible

    const float2* rv = (const float2*)(ldsraw + wv * 8704 + ln * 136);
    float mx = -3.0e38f;
#pragma unroll
    for (int k = 0; k < 16; k += 2) {
        float2 v0 = rv[k], v1 = rv[k + 1];
        mx = fmaxf(fmaxf(mx, fmaxf(v0.x, v0.y)), fmaxf(v1.x, v1.y));
    }
    atomicMax(&mm[rbase + wv * 64 + ln], enc_f(mx));
}

// Block 0: n2p loss (2048 elems, thr=0.5). Block 1: p2p loss (32768 elems, thr=0.1).
__global__ __launch_bounds__(1024) void loss_kernel(
    const float* __restrict__ hqv, const unsigned* __restrict__ mm,
    const float* __restrict__ p2p_ref, const float* __restrict__ p2p_src,
    const float* __restrict__ n2p_ref, const float* __restrict__ n2p_src,
    float* __restrict__ out)
{
    __shared__ float rc[16], rp[16], rn[16];
    bool is_p2p = (blockIdx.x == 1);
    int N = is_p2p ? 2*NF : 2*NC;
    float thr_half = is_p2p ? 0.5f*(0.1f*0.1f) : 0.5f*(0.5f*0.5f);

    float cnt = 0.0f, spos = 0.0f, sneg = 0.0f;
    for (int i = threadIdx.x; i < N; i += 1024) {
        float score; int qi;
        if (is_p2p) {
            if (i < NF) { score = p2p_src[i];      qi = NF + i; }           // src_gt: pass B
            else        { score = p2p_ref[i - NF]; qi = i - NF; }           // ref_gt: pass A
        } else {
            if (i < NC) { score = n2p_src[i];      qi = 2*NF + NC + i; }    // src_gt_n: pass D
            else        { score = n2p_ref[i - NC]; qi = 2*NF + (i - NC); }  // ref_gt_n: pass C
        }
        float maxm = dec_f(mm[qi]);
        float hq = hqv[qi];            // |q|^2 / 2 (fp32 exact)
        bool g = maxm > (hq - thr_half);
        if (g) { cnt += 1.0f; spos -= logf(score); }
        else   { sneg -= log1pf(-score); }
    }

    int lane = threadIdx.x & 63, wid = threadIdx.x >> 6;
#pragma unroll
    for (int off = 32; off > 0; off >>= 1) {
        cnt  += __shfl_down(cnt,  off, 64);
        spos += __shfl_down(spos, off, 64);
        sneg += __shfl_down(sneg, off, 64);
    }
    if (lane == 0) { rc[wid] = cnt; rp[wid] = spos; rn[wid] = sneg; }
    __syncthreads();
    if (threadIdx.x == 0) {
        float c = 0, sp = 0, sn = 0;
        for (int w = 0; w < 16; w++) { c += rc[w]; sp += rp[w]; sn += rn[w]; }
        float wneg = c / (float)N;
        float wpos = 1.0f - wneg;
        out[blockIdx.x] = (wpos * sp + wneg * sn) / (float)N;   // out[0]=n2p, out[1]=p2p
    }
}

extern "C" void kernel_launch(void* const* d_in, const int* in_sizes, int n_in,
                              void* d_out, int out_size, void* d_ws, size_t ws_size,
                              hipStream_t stream) {
    (void)in_sizes; (void)n_in; (void)out_size; (void)ws_size;
    const float* refc = (const float*)d_in[0];
    const float* srcc = (const float*)d_in[1];
    const float* reff = (const float*)d_in[2];
    const float* srcf = (const float*)d_in[3];
    const float* T    = (const float*)d_in[4];
    const float* p2p_ref = (const float*)d_in[5];
    const float* p2p_src = (const float*)d_in[6];
    const float* n2p_ref = (const float*)d_in[7];
    const float* n2p_src = (const float*)d_in[8];
    float* out = (float*)d_out;

    f16x8* a0 = (f16x8*)d_ws;
    f16x8* a1 = a0 + NPTS;
    f16x8* b0 = a1 + NPTS;
    f16x8* b1 = b0 + NPTS;
    float* hqv = (float*)(b1 + NPTS);
    unsigned* mm = (unsigned*)(hqv + NPTS);   // total ws use: 72*NPTS = ~2.5 MB

    prep_kernel<<<(NPTS + TPB - 1) / TPB, TPB, 0, stream>>>(
        refc, srcc, reff, srcf, T, a0, a1, b0, b1, hqv, mm);
    minmax_kernel<<<2176, TPB, 0, stream>>>(a0, a1, b0, b1, mm);
    loss_kernel<<<2, 1024, 0, stream>>>(hqv, mm, p2p_ref, p2p_src, n2p_ref, n2p_src, out);
}